// Round 11
// baseline (1115.134 us; speedup 1.0000x reference)
//
#include <hip/hip_runtime.h>
#include <cmath>

typedef __bf16 bf16;
typedef __attribute__((ext_vector_type(8))) __bf16 bf16x8;
typedef __attribute__((ext_vector_type(4))) __bf16 bf16x4;
typedef __attribute__((ext_vector_type(4))) float f32x4;

#define NB 2
#define NSEQ 2048
#define NDIM 512
#define NHEADS 8
#define DHEAD 64
#define NMEM 16
#define NJ 2064
#define NJP 2176        // 17*128
#define NFF 2048
#define NROWS (NB*NSEQ) // 4096
#define TBL 4111        // rel table width (rel+2047 in [0,4110])
#define JSL 544         // j-slice per mix_part block (4 slices)

enum { EPI_QKV = 0, EPI_GELUSPLIT = 1, EPI_RESID = 2 };

// ---------------------------------------------------------------------------
// Split-precision GEMM with double-buffered global_load_lds prefetch.
// ---------------------------------------------------------------------------
template<int BM, int BN, int WAVES_M, int WAVES_N, int EPI>
__global__ __launch_bounds__(256)
void gemm_split(const bf16* __restrict__ A, const bf16* __restrict__ B,
                void* __restrict__ Cv, const float* __restrict__ bias,
                void* __restrict__ Cv2, void* __restrict__ Cv3,
                int K, int lda, int ldb, int ldc, int loA, int loB)
{
  constexpr int BK = 32;
  constexpr int WM = BM / WAVES_M;
  constexpr int WN = BN / WAVES_N;
  constexpr int MF = WM / 16;
  constexpr int NF = WN / 16;
  constexpr int AI = (BM * BK * 2) / 4096;
  constexpr int BI = (BN * BK * 2) / 4096;
  __shared__ bf16 Ash[2][BM * BK];
  __shared__ bf16 Asl[2][BM * BK];
  __shared__ bf16 Bsh[2][BN * BK];
  __shared__ bf16 Bsl[2][BN * BK];

  const int bm0 = blockIdx.x * BM;
  const int bn0 = blockIdx.y * BN;
  const int t = threadIdx.x;
  const int wave = t >> 6, lane = t & 63;
  const int wr = wave / WAVES_N, wc = wave % WAVES_N;
  const int sr = t >> 2, sc = t & 3;
  const int frow = lane & 15, fk = (lane >> 4) * 8;

  auto stage = [&](int buf, int k0) {
#pragma unroll
    for (int qi = 0; qi < AI; ++qi) {
      const long long ro = (long long)(bm0 + qi * 64 + sr) * lda + (k0 + sc * 8);
      __builtin_amdgcn_global_load_lds(
          (const __attribute__((address_space(1))) void*)(A + ro),
          (__attribute__((address_space(3))) void*)(&Ash[buf][qi * 2048 + wave * 512]), 16, 0, 0);
      __builtin_amdgcn_global_load_lds(
          (const __attribute__((address_space(1))) void*)(A + ro + loA),
          (__attribute__((address_space(3))) void*)(&Asl[buf][qi * 2048 + wave * 512]), 16, 0, 0);
    }
#pragma unroll
    for (int qi = 0; qi < BI; ++qi) {
      const long long ro = (long long)(bn0 + qi * 64 + sr) * ldb + (k0 + sc * 8);
      __builtin_amdgcn_global_load_lds(
          (const __attribute__((address_space(1))) void*)(B + ro),
          (__attribute__((address_space(3))) void*)(&Bsh[buf][qi * 2048 + wave * 512]), 16, 0, 0);
      __builtin_amdgcn_global_load_lds(
          (const __attribute__((address_space(1))) void*)(B + ro + loB),
          (__attribute__((address_space(3))) void*)(&Bsl[buf][qi * 2048 + wave * 512]), 16, 0, 0);
    }
  };

  f32x4 acc[MF][NF] = {};

  stage(0, 0);
  __syncthreads();
  int cur = 0;
  for (int k0 = 0; k0 < K; k0 += BK) {
    if (k0 + BK < K) stage(cur ^ 1, k0 + BK);
    bf16x8 afh[MF], afl[MF], bfh[NF], bfl[NF];
#pragma unroll
    for (int m = 0; m < MF; m++) {
      afh[m] = *(const bf16x8*)(&Ash[cur][(wr * WM + m * 16 + frow) * BK + fk]);
      afl[m] = *(const bf16x8*)(&Asl[cur][(wr * WM + m * 16 + frow) * BK + fk]);
    }
#pragma unroll
    for (int n = 0; n < NF; n++) {
      bfh[n] = *(const bf16x8*)(&Bsh[cur][(wc * WN + n * 16 + frow) * BK + fk]);
      bfl[n] = *(const bf16x8*)(&Bsl[cur][(wc * WN + n * 16 + frow) * BK + fk]);
    }
#pragma unroll
    for (int m = 0; m < MF; m++)
#pragma unroll
      for (int n = 0; n < NF; n++) {
        acc[m][n] = __builtin_amdgcn_mfma_f32_16x16x32_bf16(afh[m], bfh[n], acc[m][n], 0, 0, 0);
        acc[m][n] = __builtin_amdgcn_mfma_f32_16x16x32_bf16(afl[m], bfh[n], acc[m][n], 0, 0, 0);
        acc[m][n] = __builtin_amdgcn_mfma_f32_16x16x32_bf16(afh[m], bfl[n], acc[m][n], 0, 0, 0);
      }
    __syncthreads();
    cur ^= 1;
  }

#pragma unroll
  for (int m = 0; m < MF; m++) {
#pragma unroll
    for (int n = 0; n < NF; n++) {
      const int row0 = bm0 + wr * WM + m * 16 + (lane >> 4) * 4;
      const int col = bn0 + wc * WN + n * 16 + (lane & 15);
#pragma unroll
      for (int r = 0; r < 4; r++) {
        const float v = acc[m][n][r];
        const long long i = row0 + r;
        if (EPI == EPI_QKV) {
          const int bb = (int)(i >> 11);
          const int il = (int)(i & 2047);
          if (col < NDIM) {
            const float vq = v * 0.125f;
            bf16* base = (bf16*)Cv;
            const long long ih = i * (long long)(2 * NDIM) + col;
            bf16 h = (bf16)vq;
            base[ih] = h;
            base[ih + NDIM] = (bf16)(vq - (float)h);
          } else if (col < 2 * NDIM) {
            bf16* ks = (bf16*)Cv3;
            const long long ih = ((long long)bb * NJP + il + NMEM) * (long long)(2 * NDIM)
                               + (col - NDIM);
            bf16 h = (bf16)v;
            ks[ih] = h;
            ks[ih + NDIM] = (bf16)(v - (float)h);
          } else {
            ((float*)Cv2)[i * (long long)NDIM + (col - 2 * NDIM)] = v;
          }
        } else if (EPI == EPI_GELUSPLIT) {
          float u = v + bias[col];
          float gl = 0.5f * u * (1.0f + erff(u * 0.7071067811865476f));
          const long long ih = i * (long long)(2 * ldc) + col;
          bf16 h = (bf16)gl;
          ((bf16*)Cv)[ih] = h;
          ((bf16*)Cv)[ih + ldc] = (bf16)(gl - (float)h);
        } else {  // EPI_RESID
          float* xp = ((float*)Cv) + i * ldc + col;
          *xp = *xp + v + bias[col];
        }
      }
    }
  }
}

// ---------------------------------------------------------------------------
// Barrier-free direct-register S-GEMM: S_h(i,j) = q_h(i).k_h(j), K=64.
// ---------------------------------------------------------------------------
__global__ __launch_bounds__(256)
void s_gemm_direct(const bf16* __restrict__ Qs, const bf16* __restrict__ Ks,
                   float* __restrict__ S)
{
  const int h = blockIdx.z;
  const int bm0 = blockIdx.x * 128;
  const int bn0 = blockIdx.y * 128;
  const int t = threadIdx.x;
  const int wave = t >> 6, lane = t & 63;
  const int wr = wave >> 1, wc = wave & 1;
  const int frow = lane & 15, fk = (lane >> 4) * 8;

  bf16x8 ah[4][2], al[4][2];
#pragma unroll
  for (int m = 0; m < 4; m++)
#pragma unroll
    for (int kk = 0; kk < 2; kk++) {
      const bf16* ap = Qs + (long long)(bm0 + wr * 64 + m * 16 + frow) * 1024
                     + h * 64 + kk * 32 + fk;
      ah[m][kk] = *(const bf16x8*)(ap);
      al[m][kk] = *(const bf16x8*)(ap + 512);
    }

  f32x4 acc[4][4] = {};
#pragma unroll
  for (int n = 0; n < 4; n++) {
    bf16x8 bh[2], bl[2];
#pragma unroll
    for (int kk = 0; kk < 2; kk++) {
      const bf16* bp = Ks + (long long)(bn0 + wc * 64 + n * 16 + frow) * 1024
                     + h * 64 + kk * 32 + fk;
      bh[kk] = *(const bf16x8*)(bp);
      bl[kk] = *(const bf16x8*)(bp + 512);
    }
#pragma unroll
    for (int m = 0; m < 4; m++)
#pragma unroll
      for (int kk = 0; kk < 2; kk++) {
        acc[m][n] = __builtin_amdgcn_mfma_f32_16x16x32_bf16(ah[m][kk], bh[kk], acc[m][n], 0, 0, 0);
        acc[m][n] = __builtin_amdgcn_mfma_f32_16x16x32_bf16(al[m][kk], bh[kk], acc[m][n], 0, 0, 0);
        acc[m][n] = __builtin_amdgcn_mfma_f32_16x16x32_bf16(ah[m][kk], bl[kk], acc[m][n], 0, 0, 0);
      }
  }

#pragma unroll
  for (int m = 0; m < 4; m++) {
#pragma unroll
    for (int n = 0; n < 4; n++) {
      const int row0 = bm0 + wr * 64 + m * 16 + (lane >> 4) * 4;
      const int col = bn0 + wc * 64 + n * 16 + (lane & 15);
#pragma unroll
      for (int r = 0; r < 4; r++)
        S[(long long)(row0 + r) * (NHEADS * NJP) + h * NJP + col] = acc[m][n][r];
    }
  }
}

// ---------------------------------------------------------------------------
// LayerNorm -> split bf16 (hi | lo), row stride 1024
// ---------------------------------------------------------------------------
__global__ __launch_bounds__(256)
void ln_kernel(const float* __restrict__ x, const float* __restrict__ g,
               const float* __restrict__ b, bf16* __restrict__ out)
{
  const int row = blockIdx.x * 4 + (threadIdx.x >> 6);
  const int lane = threadIdx.x & 63;
  const float* xr = x + (long long)row * NDIM;
  float4 a0 = ((const float4*)xr)[lane];
  float4 a1 = ((const float4*)xr)[lane + 64];
  float s = a0.x + a0.y + a0.z + a0.w + a1.x + a1.y + a1.z + a1.w;
  float ss = a0.x * a0.x + a0.y * a0.y + a0.z * a0.z + a0.w * a0.w
           + a1.x * a1.x + a1.y * a1.y + a1.z * a1.z + a1.w * a1.w;
#pragma unroll
  for (int d = 1; d < 64; d <<= 1) {
    s += __shfl_xor(s, d, 64);
    ss += __shfl_xor(ss, d, 64);
  }
  const float mean = s * (1.0f / NDIM);
  const float var = ss * (1.0f / NDIM) - mean * mean;
  const float rs = rsqrtf(var + 1e-5f);
  float4 g0 = ((const float4*)g)[lane], g1 = ((const float4*)g)[lane + 64];
  float4 b0 = ((const float4*)b)[lane], b1 = ((const float4*)b)[lane + 64];
  bf16* orow = out + (long long)row * (2 * NDIM);
  float y[8] = {
    (a0.x - mean) * rs * g0.x + b0.x, (a0.y - mean) * rs * g0.y + b0.y,
    (a0.z - mean) * rs * g0.z + b0.z, (a0.w - mean) * rs * g0.w + b0.w,
    (a1.x - mean) * rs * g1.x + b1.x, (a1.y - mean) * rs * g1.y + b1.y,
    (a1.z - mean) * rs * g1.z + b1.z, (a1.w - mean) * rs * g1.w + b1.w };
  bf16x4 h0, h1, l0, l1;
#pragma unroll
  for (int j = 0; j < 4; j++) {
    bf16 h = (bf16)y[j];      h0[j] = h;  l0[j] = (bf16)(y[j] - (float)h);
    bf16 h2 = (bf16)y[4 + j]; h1[j] = h2; l1[j] = (bf16)(y[4 + j] - (float)h2);
  }
  *(bf16x4*)(orow + lane * 4) = h0;
  *(bf16x4*)(orow + 256 + lane * 4) = h1;
  *(bf16x4*)(orow + 512 + lane * 4) = l0;
  *(bf16x4*)(orow + 768 + lane * 4) = l1;
}

// ---------------------------------------------------------------------------
// Ks edge rows: j<16 from mem_k (split), j in [2064,2176) zero. Both batches.
// ---------------------------------------------------------------------------
__global__ __launch_bounds__(256)
void ks_edges(const float* __restrict__ mem_k_l, bf16* __restrict__ Ks)
{
  const int idx = blockIdx.x * 256 + threadIdx.x;  // 2 * 128 * 512
  const int c = idx & 511;
  const int jj = (idx >> 9) & 127;
  const int bb = idx >> 16;
  const int j = (jj < NMEM) ? jj : (jj - NMEM + NJ);
  float kval = 0.f;
  if (jj < NMEM) kval = mem_k_l[((c >> 6) * NMEM + jj) * DHEAD + (c & 63)];
  bf16 hv = (bf16)kval;
  const long long ro = ((long long)bb * NJP + j) * (2 * NDIM) + c;
  Ks[ro] = hv;
  Ks[ro + NDIM] = (bf16)(kval - (float)hv);
}

// ---------------------------------------------------------------------------
// mix_part: one block = (row i, j-slice of 544). 8 waves = 8 output heads k.
// Slice working set 8h x 544 x 4B = 17.4 KB < L1, so waves 1..7 hit L1.
// Mix (bias + sum_h pk*S_h) in registers, per-lane insertion, wave butterfly
// -> slice top-8 values; ballot recovery writes (val,idx) candidates.
// ---------------------------------------------------------------------------
__global__ __launch_bounds__(512)
void mix_part(const float* __restrict__ S, const float* __restrict__ pp,
              const float* __restrict__ table2,
              float* __restrict__ cand_v, int* __restrict__ cand_i)
{
  const int i  = blockIdx.x;
  const int jb = blockIdx.y;      // 0..3
  const int k = threadIdx.x >> 6;
  const int lane = threadIdx.x & 63;
  const int base = jb * JSL;
  const float* srow = S + (long long)i * (NHEADS * NJP) + base;

  float pk[8];
#pragma unroll
  for (int h = 0; h < 8; h++) pk[h] = pp[h * 8 + k];
  const float* t2k = table2 + k * TBL + (2047 - i);

  // elements: e<4 -> jl=4*lane+e ; e<8 -> jl=256+4*lane+(e-4) ; e<12 -> jl=512+4*lane+(e-8), lane<8 only
  float v[12];
#pragma unroll
  for (int e = 0; e < 12; e++) {
    const int jl = (e < 4) ? 4 * lane + e
                 : (e < 8) ? 256 + 4 * lane + (e - 4)
                           : 512 + 4 * lane + (e - 8);
    const bool live = (e < 8) || (lane < 8);
    const int j = base + jl;
    v[e] = (live && j < NJ) ? t2k[j] : -1e30f;
  }

#pragma unroll
  for (int h = 0; h < 8; h++) {
    const float* sp = srow + h * NJP;
    const float w = pk[h];
    const float4 a = *(const float4*)(sp + 4 * lane);
    const float4 b2 = *(const float4*)(sp + 256 + 4 * lane);
    v[0] = fmaf(a.x, w, v[0]);  v[1] = fmaf(a.y, w, v[1]);
    v[2] = fmaf(a.z, w, v[2]);  v[3] = fmaf(a.w, w, v[3]);
    v[4] = fmaf(b2.x, w, v[4]); v[5] = fmaf(b2.y, w, v[5]);
    v[6] = fmaf(b2.z, w, v[6]); v[7] = fmaf(b2.w, w, v[7]);
    if (lane < 8) {
      const float4 c = *(const float4*)(sp + 512 + 4 * lane);
      v[8] = fmaf(c.x, w, v[8]);  v[9] = fmaf(c.y, w, v[9]);
      v[10] = fmaf(c.z, w, v[10]); v[11] = fmaf(c.w, w, v[11]);
    }
  }

  // branchless descending insertion over 12 elems
  float t8[8];
#pragma unroll
  for (int m = 0; m < 8; m++) t8[m] = -3.0e38f;
#pragma unroll
  for (int e = 0; e < 12; e++) {
    float x = v[e];
#pragma unroll
    for (int m = 0; m < 8; m++) {
      const float hi = fmaxf(t8[m], x);
      x = fminf(t8[m], x);
      t8[m] = hi;
    }
  }

  // values-only butterfly: slice top-8 (sorted desc) in every lane
#pragma unroll
  for (int d = 1; d < 64; d <<= 1) {
    float o[8], m8[8];
#pragma unroll
    for (int m = 0; m < 8; m++) o[m] = __shfl_xor(t8[m], d, 64);
#pragma unroll
    for (int m = 0; m < 8; m++) m8[m] = fmaxf(t8[m], o[7 - m]);
#define CX(a, bq) { float hi = fmaxf(m8[a], m8[bq]); float lo = fminf(m8[a], m8[bq]); m8[a] = hi; m8[bq] = lo; }
    CX(0, 4) CX(1, 5) CX(2, 6) CX(3, 7)
    CX(0, 2) CX(1, 3) CX(4, 6) CX(5, 7)
    CX(0, 1) CX(2, 3) CX(4, 5) CX(6, 7)
#undef CX
#pragma unroll
    for (int m = 0; m < 8; m++) t8[m] = m8[m];
  }
  const float thr = t8[7];

  // recovery: write the slice's top-8 (val, idx) candidates
  const long long cbase = (((long long)i * NHEADS + k) * 32) + jb * 8;
  int slot = 0;
  for (int e = 0; e < 12; e++) {
    if (slot >= 8) break;
    unsigned long long mball = __ballot(v[e] >= thr);
    while (mball && slot < 8) {
      const int l = __builtin_ctzll(mball);
      mball &= mball - 1;
      if (lane == l) {
        const int jl = (e < 4) ? 4 * lane + e
                     : (e < 8) ? 256 + 4 * lane + (e - 4)
                               : 512 + 4 * lane + (e - 8);
        cand_v[cbase + slot] = v[e];
        cand_i[cbase + slot] = base + jl;
      }
      slot++;
    }
  }
}

// ---------------------------------------------------------------------------
// merge_gather: per (row, k) merge 32 candidates -> global top-8, softmax,
// sparse V gather, split-bf16 output. 8 waves = 8 k per block.
// ---------------------------------------------------------------------------
__global__ __launch_bounds__(512)
void merge_gather(const float* __restrict__ cand_v, const int* __restrict__ cand_i,
                  const float* __restrict__ kvV, const float* __restrict__ mem_v_l,
                  bf16* __restrict__ obufs, int b)
{
  const int i = blockIdx.x;
  const int k = threadIdx.x >> 6;
  const int lane = threadIdx.x & 63;
  const long long cbase = ((long long)i * NHEADS + k) * 32;

  float cv = -3.0e38f;
  int ci = 0;
  if (lane < 32) {
    cv = cand_v[cbase + lane];
    ci = cand_i[cbase + lane];
  }

  float t8[8];
  t8[0] = cv;
#pragma unroll
  for (int m = 1; m < 8; m++) t8[m] = -3.0e38f;
#pragma unroll
  for (int d = 1; d < 64; d <<= 1) {
    float o[8], m8[8];
#pragma unroll
    for (int m = 0; m < 8; m++) o[m] = __shfl_xor(t8[m], d, 64);
#pragma unroll
    for (int m = 0; m < 8; m++) m8[m] = fmaxf(t8[m], o[7 - m]);
#define CX(a, bq) { float hi = fmaxf(m8[a], m8[bq]); float lo = fminf(m8[a], m8[bq]); m8[a] = hi; m8[bq] = lo; }
    CX(0, 4) CX(1, 5) CX(2, 6) CX(3, 7)
    CX(0, 2) CX(1, 3) CX(4, 6) CX(5, 7)
    CX(0, 1) CX(2, 3) CX(4, 5) CX(6, 7)
#undef CX
#pragma unroll
    for (int m = 0; m < 8; m++) t8[m] = m8[m];
  }
  const float mx = t8[0];
  const float thr = t8[7];
  float denom = 0.f;
#pragma unroll
  for (int m = 0; m < 8; m++) denom += __expf(t8[m] - mx);
  const float inv = 1.0f / denom;

  float acc = 0.f;
  unsigned long long mball = __ballot(cv >= thr);
  int cnt = 0;
  while (mball && cnt < 8) {
    const int l = __builtin_ctzll(mball);
    mball &= mball - 1;
    const int jj = __shfl(ci, l);
    const float sv = __shfl(cv, l);
    const float w = __expf(sv - mx) * inv;
    const float vv = (jj < NMEM)
        ? mem_v_l[(k * NMEM + jj) * DHEAD + lane]
        : kvV[(long long)(b * NSEQ + (jj - NMEM)) * NDIM + k * DHEAD + lane];
    acc = fmaf(w, vv, acc);
    cnt++;
  }

  const long long orow = (long long)(b * NSEQ + i) * (2 * NDIM) + k * DHEAD + lane;
  bf16 h = (bf16)acc;
  obufs[orow] = h;
  obufs[orow + NDIM] = (bf16)(acc - (float)h);
}

// ---------------------------------------------------------------------------
// fp32 weight (R x C row-major) -> split-transposed bf16 (C x 2R)
// ---------------------------------------------------------------------------
__global__ __launch_bounds__(256)
void transpose_split(const float* __restrict__ in, bf16* __restrict__ out,
                     int R, int C)
{
  const long long idx = (long long)blockIdx.x * 256 + threadIdx.x;
  if (idx >= (long long)R * C) return;
  const int r = (int)(idx / C);
  const int c = (int)(idx % C);
  float v = in[idx];
  bf16 h = (bf16)v;
  out[(long long)c * (2 * R) + r] = h;
  out[(long long)c * (2 * R) + R + r] = (bf16)(v - (float)h);
}

// ---------------------------------------------------------------------------
// T5 bias table, TRANSPOSED: table2[k][rel+2047]; exact boundaries via log2
// ---------------------------------------------------------------------------
__global__ __launch_bounds__(256)
void build_bias2(const float* __restrict__ rel_emb, float* __restrict__ table2)
{
  const int idx = blockIdx.x * 256 + threadIdx.x;
  if (idx >= 8 * TBL) return;
  const int k = idx / TBL;
  const int rel = (idx % TBL) - 2047;
  const int n = -rel;
  const int ret = (n < 0) ? 16 : 0;
  const int na = n < 0 ? -n : n;
  int bucket;
  if (na < 8) {
    bucket = ret + na;
  } else {
    int vl = 8 + (int)(log2((double)na * 0.125) * 2.0);
    vl = vl < 15 ? vl : 15;
    bucket = ret + vl;
  }
  table2[idx] = rel_emb[bucket * 8 + k];
}

// ---------------------------------------------------------------------------
extern "C" void kernel_launch(void* const* d_in, const int* in_sizes, int n_in,
                              void* d_out, int out_size, void* d_ws, size_t ws_size,
                              hipStream_t stream)
{
  const float* x_in    = (const float*)d_in[0];
  const float* ln1_g   = (const float*)d_in[1];
  const float* ln1_b   = (const float*)d_in[2];
  const float* Wq      = (const float*)d_in[3];
  const float* Wkv     = (const float*)d_in[4];
  const float* Wo      = (const float*)d_in[5];
  const float* bo      = (const float*)d_in[6];
  const float* pre_proj= (const float*)d_in[7];
  const float* mem_k   = (const float*)d_in[8];
  const float* mem_v   = (const float*)d_in[9];
  const float* ln2_g   = (const float*)d_in[10];
  const float* ln2_b   = (const float*)d_in[11];
  const float* W1      = (const float*)d_in[12];
  const float* b1      = (const float*)d_in[13];
  const float* W2      = (const float*)d_in[14];
  const float* b2      = (const float*)d_in[15];
  const float* rel_emb = (const float*)d_in[16];

  char* p = (char*)d_ws;
  auto alloc = [&](size_t bytes) -> char* {
    char* r = p;
    p += (bytes + 255) & ~(size_t)255;
    return r;
  };

  float* x    = (float*)alloc((size_t)NROWS * NDIM * 4);          // 8.4 MB
  char*  RA   = alloc((size_t)NROWS * 2 * NDIM * 2);              // 8.4 MB: hs | obufs
  bf16*  hs    = (bf16*)RA;
  bf16*  obufs = (bf16*)RA;
  char*  RB   = alloc((size_t)NROWS * 2 * NFF * 2);               // 33.6 MB: (Qs+Ks) | tbufs
  bf16*  Qs    = (bf16*)RB;
  bf16*  Ks    = (bf16*)(RB + (size_t)NROWS * 2 * NDIM * 2);
  bf16*  tbufs = (bf16*)RB;
  float* kvV  = (float*)alloc((size_t)NROWS * NDIM * 4);          // 8.4 MB (V only)
  float* S    = (float*)alloc((size_t)NSEQ * NHEADS * NJP * 4);   // 142.6 MB, [i][h][j]
  float* cand_v = (float*)alloc((size_t)NSEQ * NHEADS * 32 * 4);  // 2.1 MB
  int*   cand_i = (int*)  alloc((size_t)NSEQ * NHEADS * 32 * 4);  // 2.1 MB
  bf16*  WqkvT= (bf16*)alloc((size_t)2 * 3 * NDIM * 2 * NDIM * 2);
  bf16*  WoT  = (bf16*)alloc((size_t)2 * NDIM * 2 * NDIM * 2);
  bf16*  W1T  = (bf16*)alloc((size_t)2 * NFF * 2 * NDIM * 2);
  bf16*  W2T  = (bf16*)alloc((size_t)2 * NDIM * 2 * NFF * 2);
  float* table2= (float*)alloc((size_t)8 * TBL * 4);

  // ---- prep ----
  hipMemcpyAsync(x, x_in, (size_t)NROWS * NDIM * 4, hipMemcpyDeviceToDevice, stream);
  build_bias2<<<(8 * TBL + 255) / 256, 256, 0, stream>>>(rel_emb, table2);
  for (int l = 0; l < 2; l++) {
    bf16* WqkvT_l = WqkvT + (size_t)l * 3 * NDIM * 2 * NDIM;
    transpose_split<<<(NDIM * NDIM + 255) / 256, 256, 0, stream>>>(
        Wq + (size_t)l * NDIM * NDIM, WqkvT_l, NDIM, NDIM);
    transpose_split<<<(2 * NDIM * NDIM + 255) / 256, 256, 0, stream>>>(
        Wkv + (size_t)l * NDIM * 2 * NDIM, WqkvT_l + (size_t)NDIM * 2 * NDIM,
        NDIM, 2 * NDIM);
    transpose_split<<<(NDIM * NDIM + 255) / 256, 256, 0, stream>>>(
        Wo + (size_t)l * NDIM * NDIM, WoT + (size_t)l * NDIM * 2 * NDIM, NDIM, NDIM);
    transpose_split<<<(NDIM * NFF + 255) / 256, 256, 0, stream>>>(
        W1 + (size_t)l * NDIM * NFF, W1T + (size_t)l * NFF * 2 * NDIM, NDIM, NFF);
    transpose_split<<<(NFF * NDIM + 255) / 256, 256, 0, stream>>>(
        W2 + (size_t)l * NFF * NDIM, W2T + (size_t)l * NDIM * 2 * NFF, NFF, NDIM);
  }

  // ---- layers ----
  for (int l = 0; l < 2; l++) {
    const bf16* WqkvT_l = WqkvT + (size_t)l * 3 * NDIM * 2 * NDIM;
    const bf16* WoT_l  = WoT + (size_t)l * NDIM * 2 * NDIM;
    const bf16* W1T_l  = W1T + (size_t)l * NFF * 2 * NDIM;
    const bf16* W2T_l  = W2T + (size_t)l * NDIM * 2 * NFF;
    const float* mem_v_l = mem_v + (size_t)l * NHEADS * NMEM * DHEAD;

    ln_kernel<<<NROWS / 4, 256, 0, stream>>>(x, ln1_g + l * NDIM, ln1_b + l * NDIM, hs);
    gemm_split<128, 128, 2, 2, EPI_QKV><<<dim3(NROWS / 128, 12), 256, 0, stream>>>(
        hs, WqkvT_l, Qs, nullptr, kvV, Ks, NDIM, 2 * NDIM, 2 * NDIM, 0, NDIM, NDIM);
    ks_edges<<<(2 * 128 * 512) / 256, 256, 0, stream>>>(
        mem_k + (size_t)l * NHEADS * NMEM * DHEAD, Ks);

    for (int b = 0; b < NB; b++) {
      s_gemm_direct<<<dim3(NSEQ / 128, NJP / 128, NHEADS), 256, 0, stream>>>(
          Qs + (long long)b * NSEQ * 1024, Ks + (long long)b * NJP * 1024, S);
      mix_part<<<dim3(NSEQ, 4), 512, 0, stream>>>(
          S, pre_proj + l * 64, table2, cand_v, cand_i);
      merge_gather<<<NSEQ, 512, 0, stream>>>(
          cand_v, cand_i, kvV, mem_v_l, obufs, b);
    }

    gemm_split<128, 64, 2, 2, EPI_RESID><<<dim3(NROWS / 128, NDIM / 64), 256, 0, stream>>>(
        obufs, WoT_l, x, bo + l * NDIM, nullptr, nullptr,
        NDIM, 2 * NDIM, 2 * NDIM, NDIM, NDIM, NDIM);

    ln_kernel<<<NROWS / 4, 256, 0, stream>>>(x, ln2_g + l * NDIM, ln2_b + l * NDIM, hs);
    gemm_split<128, 128, 2, 2, EPI_GELUSPLIT><<<dim3(NROWS / 128, NFF / 128), 256, 0, stream>>>(
        hs, W1T_l, tbufs, b1 + l * NFF, nullptr, nullptr,
        NDIM, 2 * NDIM, 2 * NDIM, NFF, NDIM, NDIM);
    gemm_split<128, 64, 2, 2, EPI_RESID><<<dim3(NROWS / 128, NDIM / 64), 256, 0, stream>>>(
        tbufs, W2T_l, x, b2 + l * NDIM, nullptr, nullptr,
        NFF, 2 * NFF, 2 * NFF, NDIM, NFF, NFF);
  }

  hipMemcpyAsync(d_out, x, (size_t)out_size * 4, hipMemcpyDeviceToDevice, stream);
}

// Round 12
// 1006.071 us; speedup vs baseline: 1.1084x; 1.1084x over previous
//
#include <hip/hip_runtime.h>
#include <cmath>

typedef __bf16 bf16;
typedef __attribute__((ext_vector_type(8))) __bf16 bf16x8;
typedef __attribute__((ext_vector_type(4))) __bf16 bf16x4;
typedef __attribute__((ext_vector_type(4))) float f32x4;

#define NB 2
#define NSEQ 2048
#define NDIM 512
#define NHEADS 8
#define DHEAD 64
#define NMEM 16
#define NJ 2064
#define NJP 2176        // 17*128
#define NFF 2048
#define NROWS (NB*NSEQ) // 4096
#define TBL 4111        // rel table width (rel+2047 in [0,4110])

enum { EPI_QKV = 0, EPI_GELUSPLIT = 1, EPI_RESID = 2 };

// ---------------------------------------------------------------------------
// Split-precision GEMM with double-buffered global_load_lds prefetch.
// ---------------------------------------------------------------------------
template<int BM, int BN, int WAVES_M, int WAVES_N, int EPI>
__global__ __launch_bounds__(256)
void gemm_split(const bf16* __restrict__ A, const bf16* __restrict__ B,
                void* __restrict__ Cv, const float* __restrict__ bias,
                void* __restrict__ Cv2, void* __restrict__ Cv3,
                int K, int lda, int ldb, int ldc, int loA, int loB)
{
  constexpr int BK = 32;
  constexpr int WM = BM / WAVES_M;
  constexpr int WN = BN / WAVES_N;
  constexpr int MF = WM / 16;
  constexpr int NF = WN / 16;
  constexpr int AI = (BM * BK * 2) / 4096;
  constexpr int BI = (BN * BK * 2) / 4096;
  __shared__ bf16 Ash[2][BM * BK];
  __shared__ bf16 Asl[2][BM * BK];
  __shared__ bf16 Bsh[2][BN * BK];
  __shared__ bf16 Bsl[2][BN * BK];

  const int bm0 = blockIdx.x * BM;
  const int bn0 = blockIdx.y * BN;
  const int t = threadIdx.x;
  const int wave = t >> 6, lane = t & 63;
  const int wr = wave / WAVES_N, wc = wave % WAVES_N;
  const int sr = t >> 2, sc = t & 3;
  const int frow = lane & 15, fk = (lane >> 4) * 8;

  auto stage = [&](int buf, int k0) {
#pragma unroll
    for (int qi = 0; qi < AI; ++qi) {
      const long long ro = (long long)(bm0 + qi * 64 + sr) * lda + (k0 + sc * 8);
      __builtin_amdgcn_global_load_lds(
          (const __attribute__((address_space(1))) void*)(A + ro),
          (__attribute__((address_space(3))) void*)(&Ash[buf][qi * 2048 + wave * 512]), 16, 0, 0);
      __builtin_amdgcn_global_load_lds(
          (const __attribute__((address_space(1))) void*)(A + ro + loA),
          (__attribute__((address_space(3))) void*)(&Asl[buf][qi * 2048 + wave * 512]), 16, 0, 0);
    }
#pragma unroll
    for (int qi = 0; qi < BI; ++qi) {
      const long long ro = (long long)(bn0 + qi * 64 + sr) * ldb + (k0 + sc * 8);
      __builtin_amdgcn_global_load_lds(
          (const __attribute__((address_space(1))) void*)(B + ro),
          (__attribute__((address_space(3))) void*)(&Bsh[buf][qi * 2048 + wave * 512]), 16, 0, 0);
      __builtin_amdgcn_global_load_lds(
          (const __attribute__((address_space(1))) void*)(B + ro + loB),
          (__attribute__((address_space(3))) void*)(&Bsl[buf][qi * 2048 + wave * 512]), 16, 0, 0);
    }
  };

  f32x4 acc[MF][NF] = {};

  stage(0, 0);
  __syncthreads();
  int cur = 0;
  for (int k0 = 0; k0 < K; k0 += BK) {
    if (k0 + BK < K) stage(cur ^ 1, k0 + BK);
    bf16x8 afh[MF], afl[MF], bfh[NF], bfl[NF];
#pragma unroll
    for (int m = 0; m < MF; m++) {
      afh[m] = *(const bf16x8*)(&Ash[cur][(wr * WM + m * 16 + frow) * BK + fk]);
      afl[m] = *(const bf16x8*)(&Asl[cur][(wr * WM + m * 16 + frow) * BK + fk]);
    }
#pragma unroll
    for (int n = 0; n < NF; n++) {
      bfh[n] = *(const bf16x8*)(&Bsh[cur][(wc * WN + n * 16 + frow) * BK + fk]);
      bfl[n] = *(const bf16x8*)(&Bsl[cur][(wc * WN + n * 16 + frow) * BK + fk]);
    }
#pragma unroll
    for (int m = 0; m < MF; m++)
#pragma unroll
      for (int n = 0; n < NF; n++) {
        acc[m][n] = __builtin_amdgcn_mfma_f32_16x16x32_bf16(afh[m], bfh[n], acc[m][n], 0, 0, 0);
        acc[m][n] = __builtin_amdgcn_mfma_f32_16x16x32_bf16(afl[m], bfh[n], acc[m][n], 0, 0, 0);
        acc[m][n] = __builtin_amdgcn_mfma_f32_16x16x32_bf16(afh[m], bfl[n], acc[m][n], 0, 0, 0);
      }
    __syncthreads();
    cur ^= 1;
  }

#pragma unroll
  for (int m = 0; m < MF; m++) {
#pragma unroll
    for (int n = 0; n < NF; n++) {
      const int row0 = bm0 + wr * WM + m * 16 + (lane >> 4) * 4;
      const int col = bn0 + wc * WN + n * 16 + (lane & 15);
#pragma unroll
      for (int r = 0; r < 4; r++) {
        const float v = acc[m][n][r];
        const long long i = row0 + r;
        if (EPI == EPI_QKV) {
          const int bb = (int)(i >> 11);
          const int il = (int)(i & 2047);
          if (col < NDIM) {
            const float vq = v * 0.125f;
            bf16* base = (bf16*)Cv;
            const long long ih = i * (long long)(2 * NDIM) + col;
            bf16 h = (bf16)vq;
            base[ih] = h;
            base[ih + NDIM] = (bf16)(vq - (float)h);
          } else if (col < 2 * NDIM) {
            bf16* ks = (bf16*)Cv3;
            const long long ih = ((long long)bb * NJP + il + NMEM) * (long long)(2 * NDIM)
                               + (col - NDIM);
            bf16 h = (bf16)v;
            ks[ih] = h;
            ks[ih + NDIM] = (bf16)(v - (float)h);
          } else {
            ((float*)Cv2)[i * (long long)NDIM + (col - 2 * NDIM)] = v;
          }
        } else if (EPI == EPI_GELUSPLIT) {
          float u = v + bias[col];
          float gl = 0.5f * u * (1.0f + erff(u * 0.7071067811865476f));
          const long long ih = i * (long long)(2 * ldc) + col;
          bf16 h = (bf16)gl;
          ((bf16*)Cv)[ih] = h;
          ((bf16*)Cv)[ih + ldc] = (bf16)(gl - (float)h);
        } else {  // EPI_RESID
          float* xp = ((float*)Cv) + i * ldc + col;
          *xp = *xp + v + bias[col];
        }
      }
    }
  }
}

// ---------------------------------------------------------------------------
// Barrier-free direct-register S-GEMM: S_h(i,j) = q_h(i).k_h(j), K=64.
// ---------------------------------------------------------------------------
__global__ __launch_bounds__(256)
void s_gemm_direct(const bf16* __restrict__ Qs, const bf16* __restrict__ Ks,
                   float* __restrict__ S)
{
  const int h = blockIdx.z;
  const int bm0 = blockIdx.x * 128;
  const int bn0 = blockIdx.y * 128;
  const int t = threadIdx.x;
  const int wave = t >> 6, lane = t & 63;
  const int wr = wave >> 1, wc = wave & 1;
  const int frow = lane & 15, fk = (lane >> 4) * 8;

  bf16x8 ah[4][2], al[4][2];
#pragma unroll
  for (int m = 0; m < 4; m++)
#pragma unroll
    for (int kk = 0; kk < 2; kk++) {
      const bf16* ap = Qs + (long long)(bm0 + wr * 64 + m * 16 + frow) * 1024
                     + h * 64 + kk * 32 + fk;
      ah[m][kk] = *(const bf16x8*)(ap);
      al[m][kk] = *(const bf16x8*)(ap + 512);
    }

  f32x4 acc[4][4] = {};
#pragma unroll
  for (int n = 0; n < 4; n++) {
    bf16x8 bh[2], bl[2];
#pragma unroll
    for (int kk = 0; kk < 2; kk++) {
      const bf16* bp = Ks + (long long)(bn0 + wc * 64 + n * 16 + frow) * 1024
                     + h * 64 + kk * 32 + fk;
      bh[kk] = *(const bf16x8*)(bp);
      bl[kk] = *(const bf16x8*)(bp + 512);
    }
#pragma unroll
    for (int m = 0; m < 4; m++)
#pragma unroll
      for (int kk = 0; kk < 2; kk++) {
        acc[m][n] = __builtin_amdgcn_mfma_f32_16x16x32_bf16(ah[m][kk], bh[kk], acc[m][n], 0, 0, 0);
        acc[m][n] = __builtin_amdgcn_mfma_f32_16x16x32_bf16(al[m][kk], bh[kk], acc[m][n], 0, 0, 0);
        acc[m][n] = __builtin_amdgcn_mfma_f32_16x16x32_bf16(ah[m][kk], bl[kk], acc[m][n], 0, 0, 0);
      }
  }

#pragma unroll
  for (int m = 0; m < 4; m++) {
#pragma unroll
    for (int n = 0; n < 4; n++) {
      const int row0 = bm0 + wr * 64 + m * 16 + (lane >> 4) * 4;
      const int col = bn0 + wc * 64 + n * 16 + (lane & 15);
#pragma unroll
      for (int r = 0; r < 4; r++)
        S[(long long)(row0 + r) * (NHEADS * NJP) + h * NJP + col] = acc[m][n][r];
    }
  }
}

// ---------------------------------------------------------------------------
// LayerNorm -> split bf16 (hi | lo), row stride 1024
// ---------------------------------------------------------------------------
__global__ __launch_bounds__(256)
void ln_kernel(const float* __restrict__ x, const float* __restrict__ g,
               const float* __restrict__ b, bf16* __restrict__ out)
{
  const int row = blockIdx.x * 4 + (threadIdx.x >> 6);
  const int lane = threadIdx.x & 63;
  const float* xr = x + (long long)row * NDIM;
  float4 a0 = ((const float4*)xr)[lane];
  float4 a1 = ((const float4*)xr)[lane + 64];
  float s = a0.x + a0.y + a0.z + a0.w + a1.x + a1.y + a1.z + a1.w;
  float ss = a0.x * a0.x + a0.y * a0.y + a0.z * a0.z + a0.w * a0.w
           + a1.x * a1.x + a1.y * a1.y + a1.z * a1.z + a1.w * a1.w;
#pragma unroll
  for (int d = 1; d < 64; d <<= 1) {
    s += __shfl_xor(s, d, 64);
    ss += __shfl_xor(ss, d, 64);
  }
  const float mean = s * (1.0f / NDIM);
  const float var = ss * (1.0f / NDIM) - mean * mean;
  const float rs = rsqrtf(var + 1e-5f);
  float4 g0 = ((const float4*)g)[lane], g1 = ((const float4*)g)[lane + 64];
  float4 b0 = ((const float4*)b)[lane], b1 = ((const float4*)b)[lane + 64];
  bf16* orow = out + (long long)row * (2 * NDIM);
  float y[8] = {
    (a0.x - mean) * rs * g0.x + b0.x, (a0.y - mean) * rs * g0.y + b0.y,
    (a0.z - mean) * rs * g0.z + b0.z, (a0.w - mean) * rs * g0.w + b0.w,
    (a1.x - mean) * rs * g1.x + b1.x, (a1.y - mean) * rs * g1.y + b1.y,
    (a1.z - mean) * rs * g1.z + b1.z, (a1.w - mean) * rs * g1.w + b1.w };
  bf16x4 h0, h1, l0, l1;
#pragma unroll
  for (int j = 0; j < 4; j++) {
    bf16 h = (bf16)y[j];      h0[j] = h;  l0[j] = (bf16)(y[j] - (float)h);
    bf16 h2 = (bf16)y[4 + j]; h1[j] = h2; l1[j] = (bf16)(y[4 + j] - (float)h2);
  }
  *(bf16x4*)(orow + lane * 4) = h0;
  *(bf16x4*)(orow + 256 + lane * 4) = h1;
  *(bf16x4*)(orow + 512 + lane * 4) = l0;
  *(bf16x4*)(orow + 768 + lane * 4) = l1;
}

// ---------------------------------------------------------------------------
// Ks edge rows: j<16 from mem_k (split), j in [2064,2176) zero. Both batches.
// ---------------------------------------------------------------------------
__global__ __launch_bounds__(256)
void ks_edges(const float* __restrict__ mem_k_l, bf16* __restrict__ Ks)
{
  const int idx = blockIdx.x * 256 + threadIdx.x;  // 2 * 128 * 512
  const int c = idx & 511;
  const int jj = (idx >> 9) & 127;
  const int bb = idx >> 16;
  const int j = (jj < NMEM) ? jj : (jj - NMEM + NJ);
  float kval = 0.f;
  if (jj < NMEM) kval = mem_k_l[((c >> 6) * NMEM + jj) * DHEAD + (c & 63)];
  bf16 hv = (bf16)kval;
  const long long ro = ((long long)bb * NJP + j) * (2 * NDIM) + c;
  Ks[ro] = hv;
  Ks[ro + NDIM] = (bf16)(kval - (float)hv);
}

// ---------------------------------------------------------------------------
// 8-list values-only butterfly across 64 lanes (bitonic top-8 merge)
// ---------------------------------------------------------------------------
__device__ __forceinline__ void butterfly8(float t8[8])
{
#pragma unroll
  for (int d = 1; d < 64; d <<= 1) {
    float o[8], m8[8];
#pragma unroll
    for (int m = 0; m < 8; m++) o[m] = __shfl_xor(t8[m], d, 64);
#pragma unroll
    for (int m = 0; m < 8; m++) m8[m] = fmaxf(t8[m], o[7 - m]);
#define CX(a, bq) { float hi = fmaxf(m8[a], m8[bq]); float lo = fminf(m8[a], m8[bq]); m8[a] = hi; m8[bq] = lo; }
    CX(0, 4) CX(1, 5) CX(2, 6) CX(3, 7)
    CX(0, 2) CX(1, 3) CX(4, 6) CX(5, 7)
    CX(0, 1) CX(2, 3) CX(4, 5) CX(6, 7)
#undef CX
#pragma unroll
    for (int m = 0; m < 8; m++) t8[m] = m8[m];
  }
}

// ---------------------------------------------------------------------------
// Fused mix + bias + top-8 + softmax + sparse PV gather, k-pair x j-half.
// Block = row i, 8 waves: wave (kp,jh) reads j-half [jh*1088, ..) for all 8 h
// ONCE and mixes TWO heads k=2kp,2kp+1 (4x less L2 duplication than 1 wave
// per k reading the full row). Halves' top-8 candidates merge via 1KB LDS.
// ---------------------------------------------------------------------------
__global__ __launch_bounds__(512)
void mix_topk2(const float* __restrict__ S, const float* __restrict__ kvV,
               const float* __restrict__ mem_v_l, const float* __restrict__ pp,
               const float* __restrict__ table2, bf16* __restrict__ obufs,
               int b)
{
  __shared__ float cv_s[NHEADS][16];
  __shared__ int   ci_s[NHEADS][16];
  const int i = blockIdx.x;
  const int wv = threadIdx.x >> 6;
  const int kp = wv >> 1;          // 0..3
  const int jh = wv & 1;           // 0..1
  const int lane = threadIdx.x & 63;
  const int base = jh * 1088;
  const float* srow = S + (long long)i * (NHEADS * NJP);
  const int k0 = kp * 2, k1 = k0 + 1;

  float pk0[8], pk1[8];
#pragma unroll
  for (int h = 0; h < 8; h++) {
    pk0[h] = pp[h * 8 + k0];
    pk1[h] = pp[h * 8 + k1];
  }
  const float* t0 = table2 + k0 * TBL + (2047 - i);
  const float* t1 = table2 + k1 * TBL + (2047 - i);

  // element e -> local j offset: e<16: 256*(e>>2)+4*lane+(e&3); e==16: 1024+lane
  float va[17], vb[17];
#pragma unroll
  for (int e = 0; e < 17; e++) {
    const int jl = (e < 16) ? (256 * (e >> 2) + 4 * lane + (e & 3)) : (1024 + lane);
    const int j = base + jl;
    const bool valid = (j < NJ);
    va[e] = valid ? t0[j] : -1e30f;
    vb[e] = valid ? t1[j] : -1e30f;
  }

#pragma unroll
  for (int h = 0; h < 8; h++) {
    const float* sp = srow + h * NJP + base;
    const float w0 = pk0[h], w1 = pk1[h];
#pragma unroll
    for (int t = 0; t < 4; t++) {
      const float4 s4 = *(const float4*)(sp + 256 * t + 4 * lane);
      va[4 * t + 0] = fmaf(s4.x, w0, va[4 * t + 0]);
      va[4 * t + 1] = fmaf(s4.y, w0, va[4 * t + 1]);
      va[4 * t + 2] = fmaf(s4.z, w0, va[4 * t + 2]);
      va[4 * t + 3] = fmaf(s4.w, w0, va[4 * t + 3]);
      vb[4 * t + 0] = fmaf(s4.x, w1, vb[4 * t + 0]);
      vb[4 * t + 1] = fmaf(s4.y, w1, vb[4 * t + 1]);
      vb[4 * t + 2] = fmaf(s4.z, w1, vb[4 * t + 2]);
      vb[4 * t + 3] = fmaf(s4.w, w1, vb[4 * t + 3]);
    }
    const float st = sp[1024 + lane];
    va[16] = fmaf(st, w0, va[16]);
    vb[16] = fmaf(st, w1, vb[16]);
  }

  // per-lane branchless insertion, two lists
  float ta[8], tb[8];
#pragma unroll
  for (int m = 0; m < 8; m++) { ta[m] = -3.0e38f; tb[m] = -3.0e38f; }
#pragma unroll
  for (int e = 0; e < 17; e++) {
    float x = va[e];
#pragma unroll
    for (int m = 0; m < 8; m++) {
      const float hi = fmaxf(ta[m], x);
      x = fminf(ta[m], x);
      ta[m] = hi;
    }
    float y = vb[e];
#pragma unroll
    for (int m = 0; m < 8; m++) {
      const float hi = fmaxf(tb[m], y);
      y = fminf(tb[m], y);
      tb[m] = hi;
    }
  }
  butterfly8(ta);
  butterfly8(tb);
  const float thra = ta[7];
  const float thrb = tb[7];

  // recovery: write this half's top-8 (val,idx) to LDS
  {
    int slot = 0;
    for (int e = 0; e < 17; e++) {
      if (slot >= 8) break;
      unsigned long long mball = __ballot(va[e] >= thra);
      while (mball && slot < 8) {
        const int l = __builtin_ctzll(mball);
        mball &= mball - 1;
        if (lane == l) {
          const int jl = (e < 16) ? (256 * (e >> 2) + 4 * lane + (e & 3)) : (1024 + lane);
          cv_s[k0][jh * 8 + slot] = va[e];
          ci_s[k0][jh * 8 + slot] = base + jl;
        }
        slot++;
      }
    }
  }
  {
    int slot = 0;
    for (int e = 0; e < 17; e++) {
      if (slot >= 8) break;
      unsigned long long mball = __ballot(vb[e] >= thrb);
      while (mball && slot < 8) {
        const int l = __builtin_ctzll(mball);
        mball &= mball - 1;
        if (lane == l) {
          const int jl = (e < 16) ? (256 * (e >> 2) + 4 * lane + (e & 3)) : (1024 + lane);
          cv_s[k1][jh * 8 + slot] = vb[e];
          ci_s[k1][jh * 8 + slot] = base + jl;
        }
        slot++;
      }
    }
  }
  __syncthreads();

  if (jh != 0) return;

  // merge the two halves' candidates, softmax, gather — waves kp handle k0,k1
#pragma unroll
  for (int kk = 0; kk < 2; kk++) {
    const int k = k0 + kk;
    float cv = (lane < 16) ? cv_s[k][lane] : -3.0e38f;
    int ci = (lane < 16) ? ci_s[k][lane] : 0;
    float t8[8];
    t8[0] = cv;
#pragma unroll
    for (int m = 1; m < 8; m++) t8[m] = -3.0e38f;
    butterfly8(t8);
    const float mx = t8[0];
    const float thr = t8[7];
    float denom = 0.f;
#pragma unroll
    for (int m = 0; m < 8; m++) denom += __expf(t8[m] - mx);
    const float inv = 1.0f / denom;

    float acc = 0.f;
    unsigned long long mball = __ballot(cv >= thr);
    while (mball) {
      const int l = __builtin_ctzll(mball);
      mball &= mball - 1;
      const int jj = __shfl(ci, l);
      const float sv = __shfl(cv, l);
      const float w = __expf(sv - mx) * inv;
      const float vv = (jj < NMEM)
          ? mem_v_l[(k * NMEM + jj) * DHEAD + lane]
          : kvV[(long long)(b * NSEQ + (jj - NMEM)) * NDIM + k * DHEAD + lane];
      acc = fmaf(w, vv, acc);
    }

    const long long orow = (long long)(b * NSEQ + i) * (2 * NDIM) + k * DHEAD + lane;
    bf16 h = (bf16)acc;
    obufs[orow] = h;
    obufs[orow + NDIM] = (bf16)(acc - (float)h);
  }
}

// ---------------------------------------------------------------------------
// fp32 weight (R x C row-major) -> split-transposed bf16 (C x 2R)
// ---------------------------------------------------------------------------
__global__ __launch_bounds__(256)
void transpose_split(const float* __restrict__ in, bf16* __restrict__ out,
                     int R, int C)
{
  const long long idx = (long long)blockIdx.x * 256 + threadIdx.x;
  if (idx >= (long long)R * C) return;
  const int r = (int)(idx / C);
  const int c = (int)(idx % C);
  float v = in[idx];
  bf16 h = (bf16)v;
  out[(long long)c * (2 * R) + r] = h;
  out[(long long)c * (2 * R) + R + r] = (bf16)(v - (float)h);
}

// ---------------------------------------------------------------------------
// T5 bias table, TRANSPOSED: table2[k][rel+2047]; exact boundaries via log2
// ---------------------------------------------------------------------------
__global__ __launch_bounds__(256)
void build_bias2(const float* __restrict__ rel_emb, float* __restrict__ table2)
{
  const int idx = blockIdx.x * 256 + threadIdx.x;
  if (idx >= 8 * TBL) return;
  const int k = idx / TBL;
  const int rel = (idx % TBL) - 2047;
  const int n = -rel;
  const int ret = (n < 0) ? 16 : 0;
  const int na = n < 0 ? -n : n;
  int bucket;
  if (na < 8) {
    bucket = ret + na;
  } else {
    int vl = 8 + (int)(log2((double)na * 0.125) * 2.0);
    vl = vl < 15 ? vl : 15;
    bucket = ret + vl;
  }
  table2[idx] = rel_emb[bucket * 8 + k];
}

// ---------------------------------------------------------------------------
extern "C" void kernel_launch(void* const* d_in, const int* in_sizes, int n_in,
                              void* d_out, int out_size, void* d_ws, size_t ws_size,
                              hipStream_t stream)
{
  const float* x_in    = (const float*)d_in[0];
  const float* ln1_g   = (const float*)d_in[1];
  const float* ln1_b   = (const float*)d_in[2];
  const float* Wq      = (const float*)d_in[3];
  const float* Wkv     = (const float*)d_in[4];
  const float* Wo      = (const float*)d_in[5];
  const float* bo      = (const float*)d_in[6];
  const float* pre_proj= (const float*)d_in[7];
  const float* mem_k   = (const float*)d_in[8];
  const float* mem_v   = (const float*)d_in[9];
  const float* ln2_g   = (const float*)d_in[10];
  const float* ln2_b   = (const float*)d_in[11];
  const float* W1      = (const float*)d_in[12];
  const float* b1      = (const float*)d_in[13];
  const float* W2      = (const float*)d_in[14];
  const float* b2      = (const float*)d_in[15];
  const float* rel_emb = (const float*)d_in[16];

  char* p = (char*)d_ws;
  auto alloc = [&](size_t bytes) -> char* {
    char* r = p;
    p += (bytes + 255) & ~(size_t)255;
    return r;
  };

  float* x    = (float*)alloc((size_t)NROWS * NDIM * 4);          // 8.4 MB
  char*  RA   = alloc((size_t)NROWS * 2 * NDIM * 2);              // 8.4 MB: hs | obufs
  bf16*  hs    = (bf16*)RA;
  bf16*  obufs = (bf16*)RA;
  char*  RB   = alloc((size_t)NROWS * 2 * NFF * 2);               // 33.6 MB: (Qs+Ks) | tbufs
  bf16*  Qs    = (bf16*)RB;
  bf16*  Ks    = (bf16*)(RB + (size_t)NROWS * 2 * NDIM * 2);
  bf16*  tbufs = (bf16*)RB;
  float* kvV  = (float*)alloc((size_t)NROWS * NDIM * 4);          // 8.4 MB (V only)
  float* S    = (float*)alloc((size_t)NSEQ * NHEADS * NJP * 4);   // 142.6 MB, [i][h][j]
  bf16*  WqkvT= (bf16*)alloc((size_t)2 * 3 * NDIM * 2 * NDIM * 2);
  bf16*  WoT  = (bf16*)alloc((size_t)2 * NDIM * 2 * NDIM * 2);
  bf16*  W1T  = (bf16*)alloc((size_t)2 * NFF * 2 * NDIM * 2);
  bf16*  W2T  = (bf16*)alloc((size_t)2 * NDIM * 2 * NFF * 2);
  float* table2= (float*)alloc((size_t)8 * TBL * 4);

  // ---- prep ----
  hipMemcpyAsync(x, x_in, (size_t)NROWS * NDIM * 4, hipMemcpyDeviceToDevice, stream);
  build_bias2<<<(8 * TBL + 255) / 256, 256, 0, stream>>>(rel_emb, table2);
  for (int l = 0; l < 2; l++) {
    bf16* WqkvT_l = WqkvT + (size_t)l * 3 * NDIM * 2 * NDIM;
    transpose_split<<<(NDIM * NDIM + 255) / 256, 256, 0, stream>>>(
        Wq + (size_t)l * NDIM * NDIM, WqkvT_l, NDIM, NDIM);
    transpose_split<<<(2 * NDIM * NDIM + 255) / 256, 256, 0, stream>>>(
        Wkv + (size_t)l * NDIM * 2 * NDIM, WqkvT_l + (size_t)NDIM * 2 * NDIM,
        NDIM, 2 * NDIM);
    transpose_split<<<(NDIM * NDIM + 255) / 256, 256, 0, stream>>>(
        Wo + (size_t)l * NDIM * NDIM, WoT + (size_t)l * NDIM * 2 * NDIM, NDIM, NDIM);
    transpose_split<<<(NDIM * NFF + 255) / 256, 256, 0, stream>>>(
        W1 + (size_t)l * NDIM * NFF, W1T + (size_t)l * NFF * 2 * NDIM, NDIM, NFF);
    transpose_split<<<(NFF * NDIM + 255) / 256, 256, 0, stream>>>(
        W2 + (size_t)l * NFF * NDIM, W2T + (size_t)l * NDIM * 2 * NFF, NFF, NDIM);
  }

  // ---- layers ----
  for (int l = 0; l < 2; l++) {
    const bf16* WqkvT_l = WqkvT + (size_t)l * 3 * NDIM * 2 * NDIM;
    const bf16* WoT_l  = WoT + (size_t)l * NDIM * 2 * NDIM;
    const bf16* W1T_l  = W1T + (size_t)l * NFF * 2 * NDIM;
    const bf16* W2T_l  = W2T + (size_t)l * NDIM * 2 * NFF;
    const float* mem_v_l = mem_v + (size_t)l * NHEADS * NMEM * DHEAD;

    ln_kernel<<<NROWS / 4, 256, 0, stream>>>(x, ln1_g + l * NDIM, ln1_b + l * NDIM, hs);
    gemm_split<128, 128, 2, 2, EPI_QKV><<<dim3(NROWS / 128, 12), 256, 0, stream>>>(
        hs, WqkvT_l, Qs, nullptr, kvV, Ks, NDIM, 2 * NDIM, 2 * NDIM, 0, NDIM, NDIM);
    ks_edges<<<(2 * 128 * 512) / 256, 256, 0, stream>>>(
        mem_k + (size_t)l * NHEADS * NMEM * DHEAD, Ks);

    for (int b = 0; b < NB; b++) {
      s_gemm_direct<<<dim3(NSEQ / 128, NJP / 128, NHEADS), 256, 0, stream>>>(
          Qs + (long long)b * NSEQ * 1024, Ks + (long long)b * NJP * 1024, S);
      mix_topk2<<<NSEQ, 512, 0, stream>>>(
          S, kvV, mem_v_l, pre_proj + l * 64, table2, obufs, b);
    }

    gemm_split<128, 64, 2, 2, EPI_RESID><<<dim3(NROWS / 128, NDIM / 64), 256, 0, stream>>>(
        obufs, WoT_l, x, bo + l * NDIM, nullptr, nullptr,
        NDIM, 2 * NDIM, 2 * NDIM, NDIM, NDIM, NDIM);

    ln_kernel<<<NROWS / 4, 256, 0, stream>>>(x, ln2_g + l * NDIM, ln2_b + l * NDIM, hs);
    gemm_split<128, 128, 2, 2, EPI_GELUSPLIT><<<dim3(NROWS / 128, NFF / 128), 256, 0, stream>>>(
        hs, W1T_l, tbufs, b1 + l * NFF, nullptr, nullptr,
        NDIM, 2 * NDIM, 2 * NDIM, NFF, NDIM, NDIM);
    gemm_split<128, 64, 2, 2, EPI_RESID><<<dim3(NROWS / 128, NDIM / 64), 256, 0, stream>>>(
        tbufs, W2T_l, x, b2 + l * NDIM, nullptr, nullptr,
        NFF, 2 * NFF, 2 * NFF, NDIM, NFF, NFF);
  }

  hipMemcpyAsync(d_out, x, (size_t)out_size * 4, hipMemcpyDeviceToDevice, stream);
}

// Round 13
// 889.797 us; speedup vs baseline: 1.2532x; 1.1307x over previous
//
#include <hip/hip_runtime.h>
#include <cmath>

typedef __bf16 bf16;
typedef __attribute__((ext_vector_type(8))) __bf16 bf16x8;
typedef __attribute__((ext_vector_type(4))) __bf16 bf16x4;
typedef __attribute__((ext_vector_type(4))) float f32x4;

#define NB 2
#define NSEQ 2048
#define NDIM 512
#define NHEADS 8
#define DHEAD 64
#define NMEM 16
#define NJ 2064
#define NJP 2176        // 17*128
#define NFF 2048
#define NROWS (NB*NSEQ) // 4096
#define TBL 4111        // rel table width (rel+2047 in [0,4110])

enum { EPI_QKV = 0, EPI_GELUSPLIT = 1, EPI_RESID = 2 };

// XCD-aware chunked swizzle (requires n % 8 == 0)
__device__ __forceinline__ int xcd_swz(int bid, int n)
{
  const int cpx = n >> 3;           // chunks per XCD
  return (bid & 7) * cpx + (bid >> 3);
}

// ---------------------------------------------------------------------------
// Split-precision GEMM with double-buffered global_load_lds prefetch.
// fp32 operands stored as bf16 (hi,lo). C = Ah*Bh + Al*Bh + Ah*Bl.
// ---------------------------------------------------------------------------
template<int BM, int BN, int WAVES_M, int WAVES_N, int EPI>
__global__ __launch_bounds__(256)
void gemm_split(const bf16* __restrict__ A, const bf16* __restrict__ B,
                void* __restrict__ Cv, const float* __restrict__ bias,
                void* __restrict__ Cv2, void* __restrict__ Cv3,
                int K, int lda, int ldb, int ldc, int loA, int loB)
{
  constexpr int BK = 32;
  constexpr int WM = BM / WAVES_M;
  constexpr int WN = BN / WAVES_N;
  constexpr int MF = WM / 16;
  constexpr int NF = WN / 16;
  constexpr int AI = (BM * BK * 2) / 4096;
  constexpr int BI = (BN * BK * 2) / 4096;
  __shared__ bf16 Ash[2][BM * BK];
  __shared__ bf16 Asl[2][BM * BK];
  __shared__ bf16 Bsh[2][BN * BK];
  __shared__ bf16 Bsl[2][BN * BK];

  const int bm0 = xcd_swz(blockIdx.x, gridDim.x) * BM;   // T1: L2 locality
  const int bn0 = blockIdx.y * BN;
  const int t = threadIdx.x;
  const int wave = t >> 6, lane = t & 63;
  const int wr = wave / WAVES_N, wc = wave % WAVES_N;
  const int sr = t >> 2, sc = t & 3;
  const int frow = lane & 15, fk = (lane >> 4) * 8;

  auto stage = [&](int buf, int k0) {
#pragma unroll
    for (int qi = 0; qi < AI; ++qi) {
      const long long ro = (long long)(bm0 + qi * 64 + sr) * lda + (k0 + sc * 8);
      __builtin_amdgcn_global_load_lds(
          (const __attribute__((address_space(1))) void*)(A + ro),
          (__attribute__((address_space(3))) void*)(&Ash[buf][qi * 2048 + wave * 512]), 16, 0, 0);
      __builtin_amdgcn_global_load_lds(
          (const __attribute__((address_space(1))) void*)(A + ro + loA),
          (__attribute__((address_space(3))) void*)(&Asl[buf][qi * 2048 + wave * 512]), 16, 0, 0);
    }
#pragma unroll
    for (int qi = 0; qi < BI; ++qi) {
      const long long ro = (long long)(bn0 + qi * 64 + sr) * ldb + (k0 + sc * 8);
      __builtin_amdgcn_global_load_lds(
          (const __attribute__((address_space(1))) void*)(B + ro),
          (__attribute__((address_space(3))) void*)(&Bsh[buf][qi * 2048 + wave * 512]), 16, 0, 0);
      __builtin_amdgcn_global_load_lds(
          (const __attribute__((address_space(1))) void*)(B + ro + loB),
          (__attribute__((address_space(3))) void*)(&Bsl[buf][qi * 2048 + wave * 512]), 16, 0, 0);
    }
  };

  f32x4 acc[MF][NF] = {};

  stage(0, 0);
  __syncthreads();
  int cur = 0;
  for (int k0 = 0; k0 < K; k0 += BK) {
    if (k0 + BK < K) stage(cur ^ 1, k0 + BK);
    bf16x8 afh[MF], afl[MF], bfh[NF], bfl[NF];
#pragma unroll
    for (int m = 0; m < MF; m++) {
      afh[m] = *(const bf16x8*)(&Ash[cur][(wr * WM + m * 16 + frow) * BK + fk]);
      afl[m] = *(const bf16x8*)(&Asl[cur][(wr * WM + m * 16 + frow) * BK + fk]);
    }
#pragma unroll
    for (int n = 0; n < NF; n++) {
      bfh[n] = *(const bf16x8*)(&Bsh[cur][(wc * WN + n * 16 + frow) * BK + fk]);
      bfl[n] = *(const bf16x8*)(&Bsl[cur][(wc * WN + n * 16 + frow) * BK + fk]);
    }
#pragma unroll
    for (int m = 0; m < MF; m++)
#pragma unroll
      for (int n = 0; n < NF; n++) {
        acc[m][n] = __builtin_amdgcn_mfma_f32_16x16x32_bf16(afh[m], bfh[n], acc[m][n], 0, 0, 0);
        acc[m][n] = __builtin_amdgcn_mfma_f32_16x16x32_bf16(afl[m], bfh[n], acc[m][n], 0, 0, 0);
        acc[m][n] = __builtin_amdgcn_mfma_f32_16x16x32_bf16(afh[m], bfl[n], acc[m][n], 0, 0, 0);
      }
    __syncthreads();
    cur ^= 1;
  }

#pragma unroll
  for (int m = 0; m < MF; m++) {
#pragma unroll
    for (int n = 0; n < NF; n++) {
      const int row0 = bm0 + wr * WM + m * 16 + (lane >> 4) * 4;
      const int col = bn0 + wc * WN + n * 16 + (lane & 15);
#pragma unroll
      for (int r = 0; r < 4; r++) {
        const float v = acc[m][n][r];
        const long long i = row0 + r;
        if (EPI == EPI_QKV) {
          const int bb = (int)(i >> 11);
          const int il = (int)(i & 2047);
          if (col < NDIM) {
            const float vq = v * 0.125f;
            bf16* base = (bf16*)Cv;
            const long long ih = i * (long long)(2 * NDIM) + col;
            bf16 h = (bf16)vq;
            base[ih] = h;
            base[ih + NDIM] = (bf16)(vq - (float)h);
          } else if (col < 2 * NDIM) {
            bf16* ks = (bf16*)Cv3;
            const long long ih = ((long long)bb * NJP + il + NMEM) * (long long)(2 * NDIM)
                               + (col - NDIM);
            bf16 h = (bf16)v;
            ks[ih] = h;
            ks[ih + NDIM] = (bf16)(v - (float)h);
          } else {
            ((float*)Cv2)[i * (long long)NDIM + (col - 2 * NDIM)] = v;
          }
        } else if (EPI == EPI_GELUSPLIT) {
          float u = v + bias[col];
          float gl = 0.5f * u * (1.0f + erff(u * 0.7071067811865476f));
          const long long ih = i * (long long)(2 * ldc) + col;
          bf16 h = (bf16)gl;
          ((bf16*)Cv)[ih] = h;
          ((bf16*)Cv)[ih + ldc] = (bf16)(gl - (float)h);
        } else {  // EPI_RESID
          float* xp = ((float*)Cv) + i * ldc + col;
          *xp = *xp + v + bias[col];
        }
      }
    }
  }
}

// ---------------------------------------------------------------------------
// Barrier-free direct-register S-GEMM: S_h(i,j) = q_h(i).k_h(j), K=64.
// grid (16, 17, 8); writes S[i][h][j]. XCD swizzle on i-tiles.
// ---------------------------------------------------------------------------
__global__ __launch_bounds__(256)
void s_gemm_direct(const bf16* __restrict__ Qs, const bf16* __restrict__ Ks,
                   float* __restrict__ S)
{
  const int h = blockIdx.z;
  const int bm0 = xcd_swz(blockIdx.x, gridDim.x) * 128;
  const int bn0 = blockIdx.y * 128;
  const int t = threadIdx.x;
  const int wave = t >> 6, lane = t & 63;
  const int wr = wave >> 1, wc = wave & 1;
  const int frow = lane & 15, fk = (lane >> 4) * 8;

  bf16x8 ah[4][2], al[4][2];
#pragma unroll
  for (int m = 0; m < 4; m++)
#pragma unroll
    for (int kk = 0; kk < 2; kk++) {
      const bf16* ap = Qs + (long long)(bm0 + wr * 64 + m * 16 + frow) * 1024
                     + h * 64 + kk * 32 + fk;
      ah[m][kk] = *(const bf16x8*)(ap);
      al[m][kk] = *(const bf16x8*)(ap + 512);
    }

  f32x4 acc[4][4] = {};
#pragma unroll
  for (int n = 0; n < 4; n++) {
    bf16x8 bh[2], bl[2];
#pragma unroll
    for (int kk = 0; kk < 2; kk++) {
      const bf16* bp = Ks + (long long)(bn0 + wc * 64 + n * 16 + frow) * 1024
                     + h * 64 + kk * 32 + fk;
      bh[kk] = *(const bf16x8*)(bp);
      bl[kk] = *(const bf16x8*)(bp + 512);
    }
#pragma unroll
    for (int m = 0; m < 4; m++)
#pragma unroll
      for (int kk = 0; kk < 2; kk++) {
        acc[m][n] = __builtin_amdgcn_mfma_f32_16x16x32_bf16(ah[m][kk], bh[kk], acc[m][n], 0, 0, 0);
        acc[m][n] = __builtin_amdgcn_mfma_f32_16x16x32_bf16(al[m][kk], bh[kk], acc[m][n], 0, 0, 0);
        acc[m][n] = __builtin_amdgcn_mfma_f32_16x16x32_bf16(ah[m][kk], bl[kk], acc[m][n], 0, 0, 0);
      }
  }

#pragma unroll
  for (int m = 0; m < 4; m++) {
#pragma unroll
    for (int n = 0; n < 4; n++) {
      const int row0 = bm0 + wr * 64 + m * 16 + (lane >> 4) * 4;
      const int col = bn0 + wc * 64 + n * 16 + (lane & 15);
#pragma unroll
      for (int r = 0; r < 4; r++)
        S[(long long)(row0 + r) * (NHEADS * NJP) + h * NJP + col] = acc[m][n][r];
    }
  }
}

// ---------------------------------------------------------------------------
// LayerNorm -> split bf16 (hi | lo), row stride 1024
// ---------------------------------------------------------------------------
__global__ __launch_bounds__(256)
void ln_kernel(const float* __restrict__ x, const float* __restrict__ g,
               const float* __restrict__ b, bf16* __restrict__ out)
{
  const int row = blockIdx.x * 4 + (threadIdx.x >> 6);
  const int lane = threadIdx.x & 63;
  const float* xr = x + (long long)row * NDIM;
  float4 a0 = ((const float4*)xr)[lane];
  float4 a1 = ((const float4*)xr)[lane + 64];
  float s = a0.x + a0.y + a0.z + a0.w + a1.x + a1.y + a1.z + a1.w;
  float ss = a0.x * a0.x + a0.y * a0.y + a0.z * a0.z + a0.w * a0.w
           + a1.x * a1.x + a1.y * a1.y + a1.z * a1.z + a1.w * a1.w;
#pragma unroll
  for (int d = 1; d < 64; d <<= 1) {
    s += __shfl_xor(s, d, 64);
    ss += __shfl_xor(ss, d, 64);
  }
  const float mean = s * (1.0f / NDIM);
  const float var = ss * (1.0f / NDIM) - mean * mean;
  const float rs = rsqrtf(var + 1e-5f);
  float4 g0 = ((const float4*)g)[lane], g1 = ((const float4*)g)[lane + 64];
  float4 b0 = ((const float4*)b)[lane], b1 = ((const float4*)b)[lane + 64];
  bf16* orow = out + (long long)row * (2 * NDIM);
  float y[8] = {
    (a0.x - mean) * rs * g0.x + b0.x, (a0.y - mean) * rs * g0.y + b0.y,
    (a0.z - mean) * rs * g0.z + b0.z, (a0.w - mean) * rs * g0.w + b0.w,
    (a1.x - mean) * rs * g1.x + b1.x, (a1.y - mean) * rs * g1.y + b1.y,
    (a1.z - mean) * rs * g1.z + b1.z, (a1.w - mean) * rs * g1.w + b1.w };
  bf16x4 h0, h1, l0, l1;
#pragma unroll
  for (int j = 0; j < 4; j++) {
    bf16 h = (bf16)y[j];      h0[j] = h;  l0[j] = (bf16)(y[j] - (float)h);
    bf16 h2 = (bf16)y[4 + j]; h1[j] = h2; l1[j] = (bf16)(y[4 + j] - (float)h2);
  }
  *(bf16x4*)(orow + lane * 4) = h0;
  *(bf16x4*)(orow + 256 + lane * 4) = h1;
  *(bf16x4*)(orow + 512 + lane * 4) = l0;
  *(bf16x4*)(orow + 768 + lane * 4) = l1;
}

// ---------------------------------------------------------------------------
// Ks edge rows: j<16 from mem_k (split), j in [2064,2176) zero. Both batches.
// ---------------------------------------------------------------------------
__global__ __launch_bounds__(256)
void ks_edges(const float* __restrict__ mem_k_l, bf16* __restrict__ Ks)
{
  const int idx = blockIdx.x * 256 + threadIdx.x;  // 2 * 128 * 512
  const int c = idx & 511;
  const int jj = (idx >> 9) & 127;
  const int bb = idx >> 16;
  const int j = (jj < NMEM) ? jj : (jj - NMEM + NJ);
  float kval = 0.f;
  if (jj < NMEM) kval = mem_k_l[((c >> 6) * NMEM + jj) * DHEAD + (c & 63)];
  bf16 hv = (bf16)kval;
  const long long ro = ((long long)bb * NJP + j) * (2 * NDIM) + c;
  Ks[ro] = hv;
  Ks[ro + NDIM] = (bf16)(kval - (float)hv);
}

// ---------------------------------------------------------------------------
// Fused talking-heads mix + bias + top-8 + softmax + sparse PV gather.
// Round-10 config: barrier-free, 1 wave per output head k, full row scan.
// ---------------------------------------------------------------------------
__global__ __launch_bounds__(512)
void mix_topk_gather(const float* __restrict__ S, const float* __restrict__ kvV,
                     const float* __restrict__ mem_v_l, const float* __restrict__ pp,
                     const float* __restrict__ table2, bf16* __restrict__ obufs,
                     int b)
{
  const int i = blockIdx.x;
  const int k = threadIdx.x >> 6;
  const int lane = threadIdx.x & 63;
  const float* srow = S + (long long)i * (NHEADS * NJP);

  float pk[8];
#pragma unroll
  for (int h = 0; h < 8; h++) pk[h] = pp[h * 8 + k];
  const float* t2k = table2 + k * TBL + (2047 - i);

  float v[34];
#pragma unroll
  for (int t = 0; t < 8; t++) {
    const int j0 = 256 * t + 4 * lane;
    v[4 * t + 0] = t2k[j0];
    v[4 * t + 1] = t2k[j0 + 1];
    v[4 * t + 2] = t2k[j0 + 2];
    v[4 * t + 3] = t2k[j0 + 3];
  }
  {
    const int j0 = 2048 + 2 * lane;
    const int jc = j0 < 2062 ? j0 : 2062;
    v[32] = t2k[jc];
    v[33] = t2k[jc + 1];
  }

#pragma unroll
  for (int h = 0; h < 8; h++) {
    const float* sp = srow + h * NJP;
    const float w = pk[h];
#pragma unroll
    for (int t = 0; t < 8; t++) {
      const float4 s4 = *(const float4*)(sp + 256 * t + 4 * lane);
      v[4 * t + 0] = fmaf(s4.x, w, v[4 * t + 0]);
      v[4 * t + 1] = fmaf(s4.y, w, v[4 * t + 1]);
      v[4 * t + 2] = fmaf(s4.z, w, v[4 * t + 2]);
      v[4 * t + 3] = fmaf(s4.w, w, v[4 * t + 3]);
    }
    const float2 s2 = *(const float2*)(sp + 2048 + 2 * lane);
    v[32] = fmaf(s2.x, w, v[32]);
    v[33] = fmaf(s2.y, w, v[33]);
  }
  {
    const int j0 = 2048 + 2 * lane;
    if (j0 >= NJ) v[32] = -1e30f;
    if (j0 + 1 >= NJ) v[33] = -1e30f;
  }

  float t8[8];
#pragma unroll
  for (int m = 0; m < 8; m++) t8[m] = -3.0e38f;
#pragma unroll
  for (int e = 0; e < 34; e++) {
    float x = v[e];
#pragma unroll
    for (int m = 0; m < 8; m++) {
      const float hi = fmaxf(t8[m], x);
      x = fminf(t8[m], x);
      t8[m] = hi;
    }
  }

#pragma unroll
  for (int d = 1; d < 64; d <<= 1) {
    float o[8], m8[8];
#pragma unroll
    for (int m = 0; m < 8; m++) o[m] = __shfl_xor(t8[m], d, 64);
#pragma unroll
    for (int m = 0; m < 8; m++) m8[m] = fmaxf(t8[m], o[7 - m]);
#define CX(a, bq) { float hi = fmaxf(m8[a], m8[bq]); float lo = fminf(m8[a], m8[bq]); m8[a] = hi; m8[bq] = lo; }
    CX(0, 4) CX(1, 5) CX(2, 6) CX(3, 7)
    CX(0, 2) CX(1, 3) CX(4, 6) CX(5, 7)
    CX(0, 1) CX(2, 3) CX(4, 5) CX(6, 7)
#undef CX
#pragma unroll
    for (int m = 0; m < 8; m++) t8[m] = m8[m];
  }
  const float mx = t8[0];
  const float thr = t8[7];
  float denom = 0.f;
#pragma unroll
  for (int m = 0; m < 8; m++) denom += __expf(t8[m] - mx);
  const float inv = 1.0f / denom;

  float acc = 0.f;
#pragma unroll
  for (int t = 0; t < 8; t++) {
#pragma unroll
    for (int e = 0; e < 4; e++) {
      unsigned long long mball = __ballot(v[t * 4 + e] >= thr);
      while (mball) {
        const int l = __builtin_ctzll(mball);
        mball &= mball - 1;
        const int jj = 256 * t + 4 * l + e;
        const float sv = __shfl(v[t * 4 + e], l);
        const float w = __expf(sv - mx) * inv;
        const float vv = (jj < NMEM)
            ? mem_v_l[(k * NMEM + jj) * DHEAD + lane]
            : kvV[(long long)(b * NSEQ + (jj - NMEM)) * NDIM + k * DHEAD + lane];
        acc = fmaf(w, vv, acc);
      }
    }
  }
#pragma unroll
  for (int e = 0; e < 2; e++) {
    unsigned long long mball = __ballot(v[32 + e] >= thr);
    while (mball) {
      const int l = __builtin_ctzll(mball);
      mball &= mball - 1;
      const int jj = 2048 + 2 * l + e;
      const float sv = __shfl(v[32 + e], l);
      const float w = __expf(sv - mx) * inv;
      const float vv = (jj < NMEM)
          ? mem_v_l[(k * NMEM + jj) * DHEAD + lane]
          : kvV[(long long)(b * NSEQ + (jj - NMEM)) * NDIM + k * DHEAD + lane];
      acc = fmaf(w, vv, acc);
    }
  }

  const long long orow = (long long)(b * NSEQ + i) * (2 * NDIM) + k * DHEAD + lane;
  bf16 h = (bf16)acc;
  obufs[orow] = h;
  obufs[orow + NDIM] = (bf16)(acc - (float)h);
}

// ---------------------------------------------------------------------------
// fp32 weight (R x C row-major) -> split-transposed bf16 (C x 2R)
// ---------------------------------------------------------------------------
__global__ __launch_bounds__(256)
void transpose_split(const float* __restrict__ in, bf16* __restrict__ out,
                     int R, int C)
{
  const long long idx = (long long)blockIdx.x * 256 + threadIdx.x;
  if (idx >= (long long)R * C) return;
  const int r = (int)(idx / C);
  const int c = (int)(idx % C);
  float v = in[idx];
  bf16 h = (bf16)v;
  out[(long long)c * (2 * R) + r] = h;
  out[(long long)c * (2 * R) + R + r] = (bf16)(v - (float)h);
}

// ---------------------------------------------------------------------------
// T5 bias table, TRANSPOSED: table2[k][rel+2047]; exact boundaries via log2
// ---------------------------------------------------------------------------
__global__ __launch_bounds__(256)
void build_bias2(const float* __restrict__ rel_emb, float* __restrict__ table2)
{
  const int idx = blockIdx.x * 256 + threadIdx.x;
  if (idx >= 8 * TBL) return;
  const int k = idx / TBL;
  const int rel = (idx % TBL) - 2047;
  const int n = -rel;
  const int ret = (n < 0) ? 16 : 0;
  const int na = n < 0 ? -n : n;
  int bucket;
  if (na < 8) {
    bucket = ret + na;
  } else {
    int vl = 8 + (int)(log2((double)na * 0.125) * 2.0);
    vl = vl < 15 ? vl : 15;
    bucket = ret + vl;
  }
  table2[idx] = rel_emb[bucket * 8 + k];
}

// ---------------------------------------------------------------------------
extern "C" void kernel_launch(void* const* d_in, const int* in_sizes, int n_in,
                              void* d_out, int out_size, void* d_ws, size_t ws_size,
                              hipStream_t stream)
{
  const float* x_in    = (const float*)d_in[0];
  const float* ln1_g   = (const float*)d_in[1];
  const float* ln1_b   = (const float*)d_in[2];
  const float* Wq      = (const float*)d_in[3];
  const float* Wkv     = (const float*)d_in[4];
  const float* Wo      = (const float*)d_in[5];
  const float* bo      = (const float*)d_in[6];
  const float* pre_proj= (const float*)d_in[7];
  const float* mem_k   = (const float*)d_in[8];
  const float* mem_v   = (const float*)d_in[9];
  const float* ln2_g   = (const float*)d_in[10];
  const float* ln2_b   = (const float*)d_in[11];
  const float* W1      = (const float*)d_in[12];
  const float* b1      = (const float*)d_in[13];
  const float* W2      = (const float*)d_in[14];
  const float* b2      = (const float*)d_in[15];
  const float* rel_emb = (const float*)d_in[16];

  char* p = (char*)d_ws;
  auto alloc = [&](size_t bytes) -> char* {
    char* r = p;
    p += (bytes + 255) & ~(size_t)255;
    return r;
  };

  float* x    = (float*)alloc((size_t)NROWS * NDIM * 4);          // 8.4 MB
  char*  RA   = alloc((size_t)NROWS * 2 * NDIM * 2);              // 8.4 MB: hs | obufs
  bf16*  hs    = (bf16*)RA;
  bf16*  obufs = (bf16*)RA;
  char*  RB   = alloc((size_t)NROWS * 2 * NFF * 2);               // 33.6 MB: (Qs+Ks) | tbufs
  bf16*  Qs    = (bf16*)RB;
  bf16*  Ks    = (bf16*)(RB + (size_t)NROWS * 2 * NDIM * 2);
  bf16*  tbufs = (bf16*)RB;
  float* kvV  = (float*)alloc((size_t)NROWS * NDIM * 4);          // 8.4 MB (V only)
  float* S    = (float*)alloc((size_t)NSEQ * NHEADS * NJP * 4);   // 142.6 MB, [i][h][j]
  bf16*  WqkvT= (bf16*)alloc((size_t)2 * 3 * NDIM * 2 * NDIM * 2);
  bf16*  WoT  = (bf16*)alloc((size_t)2 * NDIM * 2 * NDIM * 2);
  bf16*  W1T  = (bf16*)alloc((size_t)2 * NFF * 2 * NDIM * 2);
  bf16*  W2T  = (bf16*)alloc((size_t)2 * NDIM * 2 * NFF * 2);
  float* table2= (float*)alloc((size_t)8 * TBL * 4);

  // ---- prep ----
  hipMemcpyAsync(x, x_in, (size_t)NROWS * NDIM * 4, hipMemcpyDeviceToDevice, stream);
  build_bias2<<<(8 * TBL + 255) / 256, 256, 0, stream>>>(rel_emb, table2);
  for (int l = 0; l < 2; l++) {
    bf16* WqkvT_l = WqkvT + (size_t)l * 3 * NDIM * 2 * NDIM;
    transpose_split<<<(NDIM * NDIM + 255) / 256, 256, 0, stream>>>(
        Wq + (size_t)l * NDIM * NDIM, WqkvT_l, NDIM, NDIM);
    transpose_split<<<(2 * NDIM * NDIM + 255) / 256, 256, 0, stream>>>(
        Wkv + (size_t)l * NDIM * 2 * NDIM, WqkvT_l + (size_t)NDIM * 2 * NDIM,
        NDIM, 2 * NDIM);
    transpose_split<<<(NDIM * NDIM + 255) / 256, 256, 0, stream>>>(
        Wo + (size_t)l * NDIM * NDIM, WoT + (size_t)l * NDIM * 2 * NDIM, NDIM, NDIM);
    transpose_split<<<(NDIM * NFF + 255) / 256, 256, 0, stream>>>(
        W1 + (size_t)l * NDIM * NFF, W1T + (size_t)l * NFF * 2 * NDIM, NDIM, NFF);
    transpose_split<<<(NFF * NDIM + 255) / 256, 256, 0, stream>>>(
        W2 + (size_t)l * NFF * NDIM, W2T + (size_t)l * NDIM * 2 * NFF, NFF, NDIM);
  }

  // ---- layers ----
  for (int l = 0; l < 2; l++) {
    const bf16* WqkvT_l = WqkvT + (size_t)l * 3 * NDIM * 2 * NDIM;
    const bf16* WoT_l  = WoT + (size_t)l * NDIM * 2 * NDIM;
    const bf16* W1T_l  = W1T + (size_t)l * NFF * 2 * NDIM;
    const bf16* W2T_l  = W2T + (size_t)l * NDIM * 2 * NFF;
    const float* mem_v_l = mem_v + (size_t)l * NHEADS * NMEM * DHEAD;

    ln_kernel<<<NROWS / 4, 256, 0, stream>>>(x, ln1_g + l * NDIM, ln1_b + l * NDIM, hs);
    gemm_split<128, 128, 2, 2, EPI_QKV><<<dim3(NROWS / 128, 12), 256, 0, stream>>>(
        hs, WqkvT_l, Qs, nullptr, kvV, Ks, NDIM, 2 * NDIM, 2 * NDIM, 0, NDIM, NDIM);
    ks_edges<<<(2 * 128 * 512) / 256, 256, 0, stream>>>(
        mem_k + (size_t)l * NHEADS * NMEM * DHEAD, Ks);

    for (int b = 0; b < NB; b++) {
      s_gemm_direct<<<dim3(NSEQ / 128, NJP / 128, NHEADS), 256, 0, stream>>>(
          Qs + (long long)b * NSEQ * 1024, Ks + (long long)b * NJP * 1024, S);
      mix_topk_gather<<<NSEQ, 512, 0, stream>>>(
          S, kvV, mem_v_l, pre_proj + l * 64, table2, obufs, b);
    }

    gemm_split<128, 64, 2, 2, EPI_RESID><<<dim3(NROWS / 128, NDIM / 64), 256, 0, stream>>>(
        obufs, WoT_l, x, bo + l * NDIM, nullptr, nullptr,
        NDIM, 2 * NDIM, 2 * NDIM, NDIM, NDIM, NDIM);

    ln_kernel<<<NROWS / 4, 256, 0, stream>>>(x, ln2_g + l * NDIM, ln2_b + l * NDIM, hs);
    gemm_split<128, 128, 2, 2, EPI_GELUSPLIT><<<dim3(NROWS / 128, NFF / 128), 256, 0, stream>>>(
        hs, W1T_l, tbufs, b1 + l * NFF, nullptr, nullptr,
        NDIM, 2 * NDIM, 2 * NDIM, NFF, NDIM, NDIM);
    gemm_split<128, 64, 2, 2, EPI_RESID><<<dim3(NROWS / 128, NDIM / 64), 256, 0, stream>>>(
        tbufs, W2T_l, x, b2 + l * NDIM, nullptr, nullptr,
        NFF, 2 * NFF, 2 * NFF, NDIM, NFF, NFF);
  }

  hipMemcpyAsync(d_out, x, (size_t)out_size * 4, hipMemcpyDeviceToDevice, stream);
}